// Round 18
// baseline (532.221 us; speedup 1.0000x reference)
//
#include <hip/hip_runtime.h>
#include <hip/hip_bf16.h>

#define N_TOK 131072
#define DIM   512
#define HID   512
#define NEXP  10

using bf16x8 = __attribute__((ext_vector_type(8))) short;
using f32x4  = __attribute__((ext_vector_type(4))) float;

__device__ __forceinline__ short f2bf(float f) {
    union { float f; unsigned u; } v; v.f = f;
    unsigned u = v.u;
    return (short)((u + 0x7FFFu + ((u >> 16) & 1u)) >> 16);   // RNE
}

// ---------------- router: logits = x @ Wr^T + br, argmax; also emits xb = bf16(x) ----------------
__global__ __launch_bounds__(256) void router_kernel(
    const float* __restrict__ x, const float* __restrict__ Wr,
    const float* __restrict__ br, int* __restrict__ eid,
    float* __restrict__ ids_out, int* __restrict__ counts,
    short* __restrict__ xb)
{
    __shared__ float wr[NEXP][DIM];
    __shared__ int lcnt[NEXP];
    int tid = threadIdx.x;
    for (int i = tid; i < NEXP * DIM / 4; i += 256)
        ((float4*)wr)[i] = ((const float4*)Wr)[i];
    if (tid < NEXP) lcnt[tid] = 0;
    __syncthreads();

    int lane  = tid & 63;
    int wave  = tid >> 6;
    int gwave = blockIdx.x * 4 + wave;
    int nwav  = gridDim.x * 4;

    for (int t = gwave; t < N_TOK; t += nwav) {
        const float4* xr = (const float4*)(x + (size_t)t * DIM);
        float4 v0 = xr[lane * 2], v1 = xr[lane * 2 + 1];
        float xf[8] = {v0.x, v0.y, v0.z, v0.w, v1.x, v1.y, v1.z, v1.w};
        bf16x8 p;
        #pragma unroll
        for (int j = 0; j < 8; ++j) p[j] = f2bf(xf[j]);
        *(bf16x8*)(xb + (size_t)t * DIM + lane * 8) = p;

        float dot[NEXP];
        #pragma unroll
        for (int e = 0; e < NEXP; ++e) {
            const float* wv = &wr[e][lane * 8];
            float s = 0.f;
            #pragma unroll
            for (int j = 0; j < 8; ++j) s = fmaf(xf[j], wv[j], s);
            dot[e] = s;
        }
        #pragma unroll
        for (int off = 32; off > 0; off >>= 1) {
            #pragma unroll
            for (int e = 0; e < NEXP; ++e) dot[e] += __shfl_xor(dot[e], off, 64);
        }
        if (lane == 0) {
            int best = 0; float bv = dot[0] + br[0];
            #pragma unroll
            for (int e = 1; e < NEXP; ++e) {
                float v = dot[e] + br[e];
                if (v > bv) { bv = v; best = e; }
            }
            eid[t] = best;
            ids_out[t] = (float)best;
            atomicAdd(&lcnt[best], 1);
        }
    }
    __syncthreads();
    if (tid < NEXP) atomicAdd(&counts[tid], lcnt[tid]);
}

// ---------------- prefix sums: token offsets + tile offsets (64-row tiles) ----------------
__global__ void offsets_kernel(const int* __restrict__ counts,
                               int* __restrict__ offsets, int* __restrict__ toff)
{
    if (threadIdx.x == 0) {
        int acc = 0, ta = 0;
        for (int e = 0; e < NEXP; ++e) {
            offsets[e] = acc; toff[e] = ta;
            acc += counts[e]; ta += (counts[e] + 63) >> 6;
        }
        offsets[NEXP] = acc; toff[NEXP] = ta;
    }
}

// ---------------- bucket scatter: perm[offset[e] + pos] = token ----------------
__global__ __launch_bounds__(256) void scatter_kernel(
    const int* __restrict__ eid, const int* __restrict__ offsets,
    int* __restrict__ cursors, int* __restrict__ perm)
{
    __shared__ int lcnt[NEXP], lbase[NEXP];
    int tid = threadIdx.x;
    if (tid < NEXP) lcnt[tid] = 0;
    __syncthreads();
    int t = blockIdx.x * 256 + tid;
    int e = 0, lpos = 0;
    if (t < N_TOK) {
        e = eid[t];
        lpos = atomicAdd(&lcnt[e], 1);
    }
    __syncthreads();
    if (tid < NEXP) lbase[tid] = atomicAdd(&cursors[tid], lcnt[tid]);
    __syncthreads();
    if (t < N_TOK) perm[offsets[e] + lbase[e] + lpos] = t;
}

// ---- transpose-convert weights: [512 k][512 n] f32 -> k-blocked bf16 [16][512 n][32 k] ----
__global__ __launch_bounds__(256) void wconvert_kernel(
    const float* __restrict__ W1, const float* __restrict__ W2,
    short* __restrict__ W1b, short* __restrict__ W2b)
{
    int mat = blockIdx.z;
    const float* src = (mat < NEXP) ? W1 + (size_t)mat * 512 * 512
                                    : W2 + (size_t)(mat - NEXP) * 512 * 512;
    short* dst = (mat < NEXP) ? W1b + (size_t)mat * 512 * 512
                              : W2b + (size_t)(mat - NEXP) * 512 * 512;
    __shared__ float tile[64][65];
    int r0 = blockIdx.y * 64, c0 = blockIdx.x * 64;   // r0 = k base, c0 = n base
    int tid = threadIdx.x;
    int tr = tid >> 4, tc4 = (tid & 15) * 4;
    #pragma unroll
    for (int i = 0; i < 4; ++i) {
        float4 v = *(const float4*)(src + (size_t)(r0 + i * 16 + tr) * 512 + c0 + tc4);
        tile[i * 16 + tr][tc4 + 0] = v.x; tile[i * 16 + tr][tc4 + 1] = v.y;
        tile[i * 16 + tr][tc4 + 2] = v.z; tile[i * 16 + tr][tc4 + 3] = v.w;
    }
    __syncthreads();
    int s   = (r0 + tc4) >> 5;     // 32k-block
    int kin = (r0 + tc4) & 31;
    #pragma unroll
    for (int i = 0; i < 4; ++i) {
        int cc = i * 16 + tr;      // n within tile
        ushort4 o;
        o.x = (ushort)f2bf(tile[tc4 + 0][cc]); o.y = (ushort)f2bf(tile[tc4 + 1][cc]);
        o.z = (ushort)f2bf(tile[tc4 + 2][cc]); o.w = (ushort)f2bf(tile[tc4 + 3][cc]);
        *(ushort4*)(dst + (size_t)s * 16384 + (size_t)(c0 + cc) * 32 + kin) = o;
    }
}

// ------------- FUSED expert FFN v3: direct-to-register dbuf, ZERO barriers in K-loops -------------
// 64 rows x 512 cols per block, 8 waves 1x8 (wave = 64 rows x 64 cols, acc[4][4]).
// L1: A/B frags loaded straight to VGPRs (explicit 2-set dbuf: set for t+1 loaded in program
//     order BEFORE step t's MFMAs -> compiler's auto-waitcnt gives a full step of latency cover).
//     W1 is L2-hot (XCD swizzle); A rows shared by all 8 waves -> L1-served.
// h -> Hb (64 KB LDS, slot^(row&7) swizzle, R17-proven). One __syncthreads.
// L2: A-frags via ds_read from Hb (compiler lgkmcnt), B direct-to-reg dbuf from W2. No barriers.
// No manual s_waitcnt anywhere (manual vmcnt would miscount the VGPR loads).
// VGPR: acc 64 + 4 frag sets 64 + addr ~40 = ~170, bound (512,2) caps 256 -> no spill.
__global__ __launch_bounds__(512, 2) void expert_fused(
    const short* __restrict__ xb, const short* __restrict__ W1,
    const short* __restrict__ W2, const float* __restrict__ b1,
    const float* __restrict__ b2,
    const int* __restrict__ offsets, const int* __restrict__ toff,
    const int* __restrict__ perm, float* __restrict__ out)
{
    // bijective XCD swizzle (m204): same-expert blocks colocate -> W L2-hot per XCD
    int nwg = gridDim.x, orig = blockIdx.x;
    int q8 = nwg >> 3, r8 = nwg & 7, xcd = orig & 7;
    int g = (xcd < r8 ? xcd * (q8 + 1) : r8 * (q8 + 1) + (xcd - r8) * q8) + (orig >> 3);
    if (g >= toff[NEXP]) return;
    int e = 0;
    #pragma unroll
    for (int k = 1; k < NEXP; ++k) e += (g >= toff[k]);
    int beg = offsets[e], cnt = offsets[e + 1] - beg;
    int m0 = (g - toff[e]) * 64;

    __shared__ char HB[65536 + 256];   // h tile (64 rows x 1024 B) + toks
    int* toks = (int*)(HB + 65536);
    int tid = threadIdx.x, lane = tid & 63, w = tid >> 6;
    if (tid < 64) toks[tid] = perm[beg + min(m0 + tid, cnt - 1)];
    __syncthreads();

    int lrow = lane & 15, kq = lane >> 4;
    const short* W1e = W1 + (size_t)e * 262144;
    const short* W2e = W2 + (size_t)e * 262144;
    int colb = w * 64;                 // wave's column base (1x8 wave layout)

    // per-lane A-frag row pointers (rows i*16+lrow), k-slice kq*8; step t -> +t*32 shorts
    const short* aP[4];
    int rA[4];
    #pragma unroll
    for (int i = 0; i < 4; ++i) {
        rA[i] = i * 16 + lrow;
        aP[i] = xb + (size_t)toks[rA[i]] * DIM + kq * 8;
    }
    // per-lane B-frag col pointers (k-blocked layout); step t -> +t*16384 shorts
    const short* bP[4];
    #pragma unroll
    for (int j = 0; j < 4; ++j)
        bP[j] = W1e + (size_t)(colb + j * 16 + lrow) * 32 + kq * 8;

    f32x4 acc[4][4];
    #pragma unroll
    for (int i = 0; i < 4; ++i)
        #pragma unroll
        for (int j = 0; j < 4; ++j) acc[i][j] = (f32x4){0.f, 0.f, 0.f, 0.f};

    bf16x8 afA[4], bvA[4], afB[4], bvB[4];

    // ================= L1: h = relu(xb . W1 + b1), no barriers =================
    #pragma unroll
    for (int i = 0; i < 4; ++i) afA[i] = *(const bf16x8*)(aP[i]);
    #pragma unroll
    for (int j = 0; j < 4; ++j) bvA[j] = *(const bf16x8*)(bP[j]);

    #pragma unroll
    for (int t = 0; t < 16; t += 2) {
        // load t+1 into B-set (program order BEFORE set-A MFMAs -> one step of cover)
        #pragma unroll
        for (int i = 0; i < 4; ++i) afB[i] = *(const bf16x8*)(aP[i] + (t + 1) * 32);
        #pragma unroll
        for (int j = 0; j < 4; ++j) bvB[j] = *(const bf16x8*)(bP[j] + (size_t)(t + 1) * 16384);
        #pragma unroll
        for (int i = 0; i < 4; ++i)
            #pragma unroll
            for (int j = 0; j < 4; ++j)
                acc[i][j] = __builtin_amdgcn_mfma_f32_16x16x32_bf16(afA[i], bvA[j], acc[i][j], 0, 0, 0);
        if (t + 2 < 16) {
            #pragma unroll
            for (int i = 0; i < 4; ++i) afA[i] = *(const bf16x8*)(aP[i] + (t + 2) * 32);
            #pragma unroll
            for (int j = 0; j < 4; ++j) bvA[j] = *(const bf16x8*)(bP[j] + (size_t)(t + 2) * 16384);
        }
        #pragma unroll
        for (int i = 0; i < 4; ++i)
            #pragma unroll
            for (int j = 0; j < 4; ++j)
                acc[i][j] = __builtin_amdgcn_mfma_f32_16x16x32_bf16(afB[i], bvB[j], acc[i][j], 0, 0, 0);
    }

    // ---- h epilogue: bias + relu -> Hb (swizzled slot = (col>>3)^(row&7), 1 KB rows) ----
    {
        const float* b1e = b1 + (size_t)e * 512;
        float bv1[4];
        #pragma unroll
        for (int j = 0; j < 4; ++j) bv1[j] = b1e[colb + j * 16 + lrow];
        #pragma unroll
        for (int i = 0; i < 4; ++i)
            #pragma unroll
            for (int q = 0; q < 4; ++q) {
                int row = i * 16 + kq * 4 + q;
                #pragma unroll
                for (int j = 0; j < 4; ++j) {
                    int col = colb + j * 16 + lrow;
                    float v = acc[i][j][q] + bv1[j];
                    v = v > 0.f ? v : 0.f;
                    *(short*)(HB + row * 1024 + (((col >> 3) ^ (row & 7)) << 4) + (col & 7) * 2) = f2bf(v);
                }
            }
    }
    __syncthreads();
    #pragma unroll
    for (int i = 0; i < 4; ++i)
        #pragma unroll
        for (int j = 0; j < 4; ++j) acc[i][j] = (f32x4){0.f, 0.f, 0.f, 0.f};

    // ================= L2: out = Hb . W2 + b2, no barriers =================
    #pragma unroll
    for (int j = 0; j < 4; ++j)
        bP[j] = W2e + (size_t)(colb + j * 16 + lrow) * 32 + kq * 8;
    int hrb[4], hx[4];
    #pragma unroll
    for (int i = 0; i < 4; ++i) { hrb[i] = rA[i] * 1024; hx[i] = rA[i] & 7; }

    #pragma unroll
    for (int i = 0; i < 4; ++i)
        afA[i] = *(const bf16x8*)(HB + hrb[i] + (((kq) ^ hx[i]) << 4));
    #pragma unroll
    for (int j = 0; j < 4; ++j) bvA[j] = *(const bf16x8*)(bP[j]);

    #pragma unroll
    for (int t = 0; t < 16; t += 2) {
        #pragma unroll
        for (int i = 0; i < 4; ++i)
            afB[i] = *(const bf16x8*)(HB + hrb[i] + ((((t + 1) * 4 + kq) ^ hx[i]) << 4));
        #pragma unroll
        for (int j = 0; j < 4; ++j) bvB[j] = *(const bf16x8*)(bP[j] + (size_t)(t + 1) * 16384);
        #pragma unroll
        for (int i = 0; i < 4; ++i)
            #pragma unroll
            for (int j = 0; j < 4; ++j)
                acc[i][j] = __builtin_amdgcn_mfma_f32_16x16x32_bf16(afA[i], bvA[j], acc[i][j], 0, 0, 0);
        if (t + 2 < 16) {
            #pragma unroll
            for (int i = 0; i < 4; ++i)
                afA[i] = *(const bf16x8*)(HB + hrb[i] + ((((t + 2) * 4 + kq) ^ hx[i]) << 4));
            #pragma unroll
            for (int j = 0; j < 4; ++j) bvA[j] = *(const bf16x8*)(bP[j] + (size_t)(t + 2) * 16384);
        }
        #pragma unroll
        for (int i = 0; i < 4; ++i)
            #pragma unroll
            for (int j = 0; j < 4; ++j)
                acc[i][j] = __builtin_amdgcn_mfma_f32_16x16x32_bf16(afB[i], bvB[j], acc[i][j], 0, 0, 0);
    }

    // ---- final epilogue: bias + f32 scatter ----
    {
        const float* b2e = b2 + (size_t)e * 512;
        float bv2[4];
        #pragma unroll
        for (int j = 0; j < 4; ++j) bv2[j] = b2e[colb + j * 16 + lrow];
        #pragma unroll
        for (int i = 0; i < 4; ++i)
            #pragma unroll
            for (int q = 0; q < 4; ++q) {
                int row = i * 16 + kq * 4 + q;
                if (m0 + row < cnt) {
                    float* op = out + (size_t)toks[row] * HID;
                    #pragma unroll
                    for (int j = 0; j < 4; ++j)
                        op[colb + j * 16 + lrow] = acc[i][j][q] + bv2[j];
                }
            }
    }
}

extern "C" void kernel_launch(void* const* d_in, const int* in_sizes, int n_in,
                              void* d_out, int out_size, void* d_ws, size_t ws_size,
                              hipStream_t stream)
{
    const float* x  = (const float*)d_in[0];
    const float* Wr = (const float*)d_in[1];
    const float* br = (const float*)d_in[2];
    const float* W1 = (const float*)d_in[3];
    const float* b1 = (const float*)d_in[4];
    const float* W2 = (const float*)d_in[5];
    const float* b2 = (const float*)d_in[6];

    float* out     = (float*)d_out;
    float* ids_out = out + (size_t)N_TOK * HID;

    char* ws     = (char*)d_ws;
    int* counts  = (int*)ws;            // 16 ints
    int* offsets = counts + 16;         // 11 used
    int* toff    = counts + 32;         // 11 used
    int* cursors = counts + 48;         // 16
    int* eid     = (int*)(ws + 1024);
    int* perm    = eid + N_TOK;
    short* W1b   = (short*)(ws + 1024 + (size_t)2 * N_TOK * 4);
    short* W2b   = W1b + (size_t)NEXP * 512 * 512;
    short* xb    = W2b + (size_t)NEXP * 512 * 512;

    (void)hipMemsetAsync(d_ws, 0, 1024, stream);
    router_kernel<<<2048, 256, 0, stream>>>(x, Wr, br, eid, ids_out, counts, xb);
    wconvert_kernel<<<dim3(8, 8, 2 * NEXP), 256, 0, stream>>>(W1, W2, W1b, W2b);
    offsets_kernel<<<1, 64, 0, stream>>>(counts, offsets, toff);
    scatter_kernel<<<512, 256, 0, stream>>>(eid, offsets, cursors, perm);

    int ntiles = (N_TOK + 63) / 64 + NEXP;   // upper bound on 64-row tiles (2058)
    expert_fused<<<ntiles, 512, 0, stream>>>(xb, W1b, W2b, b1, b2,
                                             offsets, toff, perm, out);
}

// Round 19
// 357.018 us; speedup vs baseline: 1.4907x; 1.4907x over previous
//
#include <hip/hip_runtime.h>
#include <hip/hip_bf16.h>

#define N_TOK 131072
#define DIM   512
#define HID   512
#define NEXP  10

using bf16x8 = __attribute__((ext_vector_type(8))) short;
using f32x4  = __attribute__((ext_vector_type(4))) float;

__device__ __forceinline__ short f2bf(float f) {
    union { float f; unsigned u; } v; v.f = f;
    unsigned u = v.u;
    return (short)((u + 0x7FFFu + ((u >> 16) & 1u)) >> 16);   // RNE
}

#define GLOAD16(g, l) __builtin_amdgcn_global_load_lds( \
    (const __attribute__((address_space(1))) void*)(g),  \
    (__attribute__((address_space(3))) void*)(l), 16, 0, 0)

// ---------------- router: logits = x @ Wr^T + br, argmax; also emits xb = bf16(x) ----------------
__global__ __launch_bounds__(256) void router_kernel(
    const float* __restrict__ x, const float* __restrict__ Wr,
    const float* __restrict__ br, int* __restrict__ eid,
    float* __restrict__ ids_out, int* __restrict__ counts,
    short* __restrict__ xb)
{
    __shared__ float wr[NEXP][DIM];
    __shared__ int lcnt[NEXP];
    int tid = threadIdx.x;
    for (int i = tid; i < NEXP * DIM / 4; i += 256)
        ((float4*)wr)[i] = ((const float4*)Wr)[i];
    if (tid < NEXP) lcnt[tid] = 0;
    __syncthreads();

    int lane  = tid & 63;
    int wave  = tid >> 6;
    int gwave = blockIdx.x * 4 + wave;
    int nwav  = gridDim.x * 4;

    for (int t = gwave; t < N_TOK; t += nwav) {
        const float4* xr = (const float4*)(x + (size_t)t * DIM);
        float4 v0 = xr[lane * 2], v1 = xr[lane * 2 + 1];
        float xf[8] = {v0.x, v0.y, v0.z, v0.w, v1.x, v1.y, v1.z, v1.w};
        bf16x8 p;
        #pragma unroll
        for (int j = 0; j < 8; ++j) p[j] = f2bf(xf[j]);
        *(bf16x8*)(xb + (size_t)t * DIM + lane * 8) = p;

        float dot[NEXP];
        #pragma unroll
        for (int e = 0; e < NEXP; ++e) {
            const float* wv = &wr[e][lane * 8];
            float s = 0.f;
            #pragma unroll
            for (int j = 0; j < 8; ++j) s = fmaf(xf[j], wv[j], s);
            dot[e] = s;
        }
        #pragma unroll
        for (int off = 32; off > 0; off >>= 1) {
            #pragma unroll
            for (int e = 0; e < NEXP; ++e) dot[e] += __shfl_xor(dot[e], off, 64);
        }
        if (lane == 0) {
            int best = 0; float bv = dot[0] + br[0];
            #pragma unroll
            for (int e = 1; e < NEXP; ++e) {
                float v = dot[e] + br[e];
                if (v > bv) { bv = v; best = e; }
            }
            eid[t] = best;
            ids_out[t] = (float)best;
            atomicAdd(&lcnt[best], 1);
        }
    }
    __syncthreads();
    if (tid < NEXP) atomicAdd(&counts[tid], lcnt[tid]);
}

// ---------------- bucket scatter: perm[offset[e] + pos] = token ----------------
__global__ __launch_bounds__(256) void scatter_kernel(
    const int* __restrict__ eid, const int* __restrict__ offsets,
    int* __restrict__ cursors, int* __restrict__ perm)
{
    __shared__ int lcnt[NEXP], lbase[NEXP];
    int tid = threadIdx.x;
    if (tid < NEXP) lcnt[tid] = 0;
    __syncthreads();
    int t = blockIdx.x * 256 + tid;
    int e = 0, lpos = 0;
    if (t < N_TOK) {
        e = eid[t];
        lpos = atomicAdd(&lcnt[e], 1);
    }
    __syncthreads();
    if (tid < NEXP) lbase[tid] = atomicAdd(&cursors[tid], lcnt[tid]);
    __syncthreads();
    if (t < N_TOK) perm[offsets[e] + lbase[e] + lpos] = t;
}

// ---- transpose-convert weights -> k-blocked bf16 [16][512 n][32 k]; block 0 also does offsets ----
// (counts is final: router completes before this kernel in stream order)
__global__ __launch_bounds__(256) void wconvert_kernel(
    const float* __restrict__ W1, const float* __restrict__ W2,
    short* __restrict__ W1b, short* __restrict__ W2b,
    const int* __restrict__ counts, int* __restrict__ offsets, int* __restrict__ toff)
{
    if (blockIdx.x == 0 && blockIdx.y == 0 && blockIdx.z == 0 && threadIdx.x == 0) {
        int acc = 0, ta = 0;
        for (int e = 0; e < NEXP; ++e) {
            offsets[e] = acc; toff[e] = ta;
            acc += counts[e]; ta += (counts[e] + 63) >> 6;
        }
        offsets[NEXP] = acc; toff[NEXP] = ta;
    }
    int mat = blockIdx.z;
    const float* src = (mat < NEXP) ? W1 + (size_t)mat * 512 * 512
                                    : W2 + (size_t)(mat - NEXP) * 512 * 512;
    short* dst = (mat < NEXP) ? W1b + (size_t)mat * 512 * 512
                              : W2b + (size_t)(mat - NEXP) * 512 * 512;
    __shared__ float tile[64][65];
    int r0 = blockIdx.y * 64, c0 = blockIdx.x * 64;   // r0 = k base, c0 = n base
    int tid = threadIdx.x;
    int tr = tid >> 4, tc4 = (tid & 15) * 4;
    #pragma unroll
    for (int i = 0; i < 4; ++i) {
        float4 v = *(const float4*)(src + (size_t)(r0 + i * 16 + tr) * 512 + c0 + tc4);
        tile[i * 16 + tr][tc4 + 0] = v.x; tile[i * 16 + tr][tc4 + 1] = v.y;
        tile[i * 16 + tr][tc4 + 2] = v.z; tile[i * 16 + tr][tc4 + 3] = v.w;
    }
    __syncthreads();
    int s   = (r0 + tc4) >> 5;     // 32k-block
    int kin = (r0 + tc4) & 31;
    #pragma unroll
    for (int i = 0; i < 4; ++i) {
        int cc = i * 16 + tr;      // n within tile
        ushort4 o;
        o.x = (ushort)f2bf(tile[tc4 + 0][cc]); o.y = (ushort)f2bf(tile[tc4 + 1][cc]);
        o.z = (ushort)f2bf(tile[tc4 + 2][cc]); o.w = (ushort)f2bf(tile[tc4 + 3][cc]);
        *(ushort4*)(dst + (size_t)s * 16384 + (size_t)(c0 + cc) * 32 + kin) = o;
    }
}

// ---------------- FUSED expert FFN v2 (R17-proven, 359 us): 64 rows x 512 cols per block ----------------
// L1 (16 steps): h = relu(xb[toks] . W1 + b1) -> Hb (64 KB LDS, slot^(row&7) swizzle, 1KB rows)
// L2 (16 steps): out = Hb . W2 + b2 -> f32 scatter. A-frags from Hb (no staging).
// Ledger (2-buffer counted-vmcnt): L1 even t = 5 issues, odd = 4; waits vmcnt(5)/(4), tail 0.
// L2: 4 loads/step, vmcnt(4), tail 0. One reused acc[2][8] (64 VGPR) -> no spill (VGPR 88 measured).
__global__ __launch_bounds__(512, 2) void expert_fused(
    const short* __restrict__ xb, const short* __restrict__ W1,
    const short* __restrict__ W2, const float* __restrict__ b1,
    const float* __restrict__ b2,
    const int* __restrict__ offsets, const int* __restrict__ toff,
    const int* __restrict__ perm, float* __restrict__ out)
{
    // bijective XCD swizzle (m204)
    int nwg = gridDim.x, orig = blockIdx.x;
    int q8 = nwg >> 3, r8 = nwg & 7, xcd = orig & 7;
    int g = (xcd < r8 ? xcd * (q8 + 1) : r8 * (q8 + 1) + (xcd - r8) * q8) + (orig >> 3);
    if (g >= toff[NEXP]) return;
    int e = 0;
    #pragma unroll
    for (int k = 1; k < NEXP; ++k) e += (g >= toff[k]);
    int beg = offsets[e], cnt = offsets[e + 1] - beg;
    int m0 = (g - toff[e]) * 64;

    // LDS: A pair-bufs [0,16K) ; B dbuf [16K,80K) ; Hb [80K,144K) ; toks @144K
    __shared__ char SMEM[147712];
    #define ABUF(b) (SMEM + (b) * 8192)
    #define BBUF(b) (SMEM + 16384 + (b) * 32768)
    #define HBUF    (SMEM + 81920)

    int tid = threadIdx.x, lane = tid & 63, w = tid >> 6;
    int* toks = (int*)(SMEM + 147456);
    if (tid < 64) toks[tid] = perm[beg + min(m0 + tid, cnt - 1)];
    __syncthreads();

    const short* W1e = W1 + (size_t)e * 262144;
    const short* W2e = W2 + (size_t)e * 262144;

    // ---- staging addresses (source pre-swizzled; LDS dest linear) ----
    int arow = tid >> 3, asl = tid & 7;
    int aql  = asl ^ (arow & 7);                       // logical 8-slot within 64-k pair
    const short* aS = xb + (size_t)toks[arow] * DIM + aql * 8;   // + pair*64
    int boff[4];
    #pragma unroll
    for (int i = 0; i < 4; ++i) {
        int sid = tid + i * 512, c = sid >> 2, qq = sid & 3;
        boff[i] = c * 32 + (qq ^ ((c >> 1) & 3)) * 8;  // shorts; + t*16384
    }

    // ---- fragment read constants ----
    int wr = w >> 2, wc = w & 3, lrow = lane & 15, kq = lane >> 4;
    int rA[2];
    #pragma unroll
    for (int i = 0; i < 2; ++i) rA[i] = wr * 32 + i * 16 + lrow;
    int offB[8];
    #pragma unroll
    for (int j = 0; j < 8; ++j) {
        int c = wc * 128 + j * 16 + lrow;
        offB[j] = c * 64 + ((kq ^ ((c >> 1) & 3)) << 4);
    }

    f32x4 acc[2][8];
    #pragma unroll
    for (int i = 0; i < 2; ++i)
        #pragma unroll
        for (int j = 0; j < 8; ++j) acc[i][j] = (f32x4){0.f, 0.f, 0.f, 0.f};

    // ================= L1: h = relu(xb.W1 + b1) =================
    // prologue: B0 (4), A0 (1), B1 (4) -> wait vmcnt(4) leaves B1 in flight
    {
        #pragma unroll
        for (int i_ = 0; i_ < 4; ++i_) GLOAD16(W1e + boff[i_], BBUF(0) + tid * 16 + i_ * 8192);
        GLOAD16(aS, ABUF(0) + tid * 16);
        #pragma unroll
        for (int i_ = 0; i_ < 4; ++i_) GLOAD16(W1e + 16384 + boff[i_], BBUF(1) + tid * 16 + i_ * 8192);
    }
    asm volatile("s_waitcnt vmcnt(4)" ::: "memory");   // B0 + A0 resident
    __builtin_amdgcn_s_barrier();

    #pragma unroll
    for (int t = 0; t < 16; ++t) {
        // comp(t): B from BBUF(t&1), A from ABUF((t>>1)&1) at k-half (t&1)
        {
            bf16x8 af[2], bv[8];
            #pragma unroll
            for (int j = 0; j < 8; ++j) bv[j] = *(const bf16x8*)(BBUF(t & 1) + offB[j]);
            #pragma unroll
            for (int i = 0; i < 2; ++i) {
                int sl = (((t & 1) * 4 + kq) ^ (rA[i] & 7));
                af[i] = *(const bf16x8*)(ABUF((t >> 1) & 1) + rA[i] * 128 + sl * 16);
            }
            __builtin_amdgcn_s_setprio(1);
            #pragma unroll
            for (int i = 0; i < 2; ++i)
                #pragma unroll
                for (int j = 0; j < 8; ++j)
                    acc[i][j] = __builtin_amdgcn_mfma_f32_16x16x32_bf16(af[i], bv[j], acc[i][j], 0, 0, 0);
            __builtin_amdgcn_s_setprio(0);
        }
        if (t == 15) break;
        __builtin_amdgcn_s_barrier();                  // barrier A: buf t&1 reads done
        asm volatile("" ::: "memory");
        if (t + 2 < 16) {
            #pragma unroll
            for (int i_ = 0; i_ < 4; ++i_)
                GLOAD16(W1e + (t + 2) * 16384 + boff[i_], BBUF(t & 1) + tid * 16 + i_ * 8192);
            if ((t & 1) == 0) {
                GLOAD16(aS + (t / 2 + 1) * 64, ABUF((t / 2 + 1) & 1) + tid * 16);
                asm volatile("s_waitcnt vmcnt(5)" ::: "memory");   // step t+1 data resident
            } else {
                asm volatile("s_waitcnt vmcnt(4)" ::: "memory");
            }
        } else {
            asm volatile("s_waitcnt vmcnt(0)" ::: "memory");       // drain B(15)
        }
        __builtin_amdgcn_s_barrier();                  // barrier B: buf (t+1)&1 ready
    }

    // ---- h epilogue: bias + relu -> Hb (swizzled), then reset acc ----
    {
        const float* b1e = b1 + (size_t)e * 512;
        float bv1[8];
        #pragma unroll
        for (int j = 0; j < 8; ++j) bv1[j] = b1e[wc * 128 + j * 16 + lrow];
        #pragma unroll
        for (int i = 0; i < 2; ++i)
            #pragma unroll
            for (int q = 0; q < 4; ++q) {
                int row = wr * 32 + i * 16 + kq * 4 + q;
                #pragma unroll
                for (int j = 0; j < 8; ++j) {
                    int col = wc * 128 + j * 16 + lrow;
                    float v = acc[i][j][q] + bv1[j];
                    v = v > 0.f ? v : 0.f;
                    *(short*)(HBUF + row * 1024 + (((col >> 3) ^ (row & 7)) << 4) + (col & 7) * 2) = f2bf(v);
                }
            }
    }
    __syncthreads();
    #pragma unroll
    for (int i = 0; i < 2; ++i)
        #pragma unroll
        for (int j = 0; j < 8; ++j) acc[i][j] = (f32x4){0.f, 0.f, 0.f, 0.f};

    // ================= L2: out = Hb . W2 + b2 =================
    {
        #pragma unroll
        for (int i_ = 0; i_ < 4; ++i_) GLOAD16(W2e + boff[i_], BBUF(0) + tid * 16 + i_ * 8192);
        #pragma unroll
        for (int i_ = 0; i_ < 4; ++i_) GLOAD16(W2e + 16384 + boff[i_], BBUF(1) + tid * 16 + i_ * 8192);
    }
    asm volatile("s_waitcnt vmcnt(4)" ::: "memory");
    __builtin_amdgcn_s_barrier();

    #pragma unroll
    for (int t = 0; t < 16; ++t) {
        {
            bf16x8 af[2], bv[8];
            #pragma unroll
            for (int j = 0; j < 8; ++j) bv[j] = *(const bf16x8*)(BBUF(t & 1) + offB[j]);
            #pragma unroll
            for (int i = 0; i < 2; ++i) {
                int s = (t * 4 + kq) ^ (rA[i] & 7);
                af[i] = *(const bf16x8*)(HBUF + rA[i] * 1024 + (s << 4));
            }
            __builtin_amdgcn_s_setprio(1);
            #pragma unroll
            for (int i = 0; i < 2; ++i)
                #pragma unroll
                for (int j = 0; j < 8; ++j)
                    acc[i][j] = __builtin_amdgcn_mfma_f32_16x16x32_bf16(af[i], bv[j], acc[i][j], 0, 0, 0);
            __builtin_amdgcn_s_setprio(0);
        }
        if (t == 15) break;
        __builtin_amdgcn_s_barrier();
        asm volatile("" ::: "memory");
        if (t + 2 < 16) {
            #pragma unroll
            for (int i_ = 0; i_ < 4; ++i_)
                GLOAD16(W2e + (t + 2) * 16384 + boff[i_], BBUF(t & 1) + tid * 16 + i_ * 8192);
            asm volatile("s_waitcnt vmcnt(4)" ::: "memory");
        } else {
            asm volatile("s_waitcnt vmcnt(0)" ::: "memory");
        }
        __builtin_amdgcn_s_barrier();
    }

    // ---- final epilogue: bias + f32 scatter ----
    {
        const float* b2e = b2 + (size_t)e * 512;
        float bv2[8];
        #pragma unroll
        for (int j = 0; j < 8; ++j) bv2[j] = b2e[wc * 128 + j * 16 + lrow];
        #pragma unroll
        for (int i = 0; i < 2; ++i)
            #pragma unroll
            for (int q = 0; q < 4; ++q) {
                int row = wr * 32 + i * 16 + kq * 4 + q;
                if (m0 + row < cnt) {
                    float* op = out + (size_t)toks[row] * HID;
                    #pragma unroll
                    for (int j = 0; j < 8; ++j)
                        op[wc * 128 + j * 16 + lrow] = acc[i][j][q] + bv2[j];
                }
            }
    }
    #undef ABUF
    #undef BBUF
    #undef HBUF
}

extern "C" void kernel_launch(void* const* d_in, const int* in_sizes, int n_in,
                              void* d_out, int out_size, void* d_ws, size_t ws_size,
                              hipStream_t stream)
{
    const float* x  = (const float*)d_in[0];
    const float* Wr = (const float*)d_in[1];
    const float* br = (const float*)d_in[2];
    const float* W1 = (const float*)d_in[3];
    const float* b1 = (const float*)d_in[4];
    const float* W2 = (const float*)d_in[5];
    const float* b2 = (const float*)d_in[6];

    float* out     = (float*)d_out;
    float* ids_out = out + (size_t)N_TOK * HID;

    char* ws     = (char*)d_ws;
    int* counts  = (int*)ws;            // 16 ints
    int* offsets = counts + 16;         // 11 used
    int* toff    = counts + 32;         // 11 used
    int* cursors = counts + 48;         // 16
    int* eid     = (int*)(ws + 1024);
    int* perm    = eid + N_TOK;
    short* W1b   = (short*)(ws + 1024 + (size_t)2 * N_TOK * 4);
    short* W2b   = W1b + (size_t)NEXP * 512 * 512;
    short* xb    = W2b + (size_t)NEXP * 512 * 512;

    (void)hipMemsetAsync(d_ws, 0, 1024, stream);
    router_kernel<<<2048, 256, 0, stream>>>(x, Wr, br, eid, ids_out, counts, xb);
    wconvert_kernel<<<dim3(8, 8, 2 * NEXP), 256, 0, stream>>>(W1, W2, W1b, W2b,
                                                              counts, offsets, toff);
    scatter_kernel<<<512, 256, 0, stream>>>(eid, offsets, cursors, perm);

    int ntiles = (N_TOK + 63) / 64 + NEXP;   // upper bound on 64-row tiles (2058)
    expert_fused<<<ntiles, 512, 0, stream>>>(xb, W1b, W2b, b1, b2,
                                             offsets, toff, perm, out);
}